// Round 14
// baseline (222.862 us; speedup 1.0000x reference)
//
#include <hip/hip_runtime.h>
#include <hip/hip_bf16.h>
#include <stdint.h>

typedef short bf16x8 __attribute__((ext_vector_type(8)));
typedef short bf16x4 __attribute__((ext_vector_type(4)));
typedef float f32x4 __attribute__((ext_vector_type(4)));

#define HD 64
#define NH 16
#define SEQ 2048
#define BATCH 2
#define DM 1024
#define TOK (BATCH * SEQ)

__device__ __forceinline__ unsigned short f2bf(float f) {
    union { float f; unsigned u; } a; a.f = f;
    unsigned r = a.u + 0x7fffu + ((a.u >> 16) & 1u);
    return (unsigned short)(r >> 16);
}
__device__ __forceinline__ float bf2f(unsigned short u) {
    union { unsigned u; float f; } a; a.u = ((unsigned)u) << 16;
    return a.f;
}

// HW-packed 2xf32 -> 2xbf16 (v_cvt_pk_bf16_f32 on gfx950; one VALU op).
__device__ __forceinline__ unsigned pkbf16(float a, float b) {
    union { __hip_bfloat162 h; unsigned u; } cv;
    cv.h = __float22bfloat162_rn(make_float2(a, b));
    return cv.u;
}

__device__ __forceinline__ float fexp2(float x) {
#if __has_builtin(__builtin_amdgcn_exp2f)
    return __builtin_amdgcn_exp2f(x);
#else
    return exp2f(x);
#endif
}
__device__ __forceinline__ float frcp(float x) {
#if __has_builtin(__builtin_amdgcn_rcpf)
    return __builtin_amdgcn_rcpf(x);
#else
    return 1.0f / x;
#endif
}

// 16x16x16 bf16 MFMA (2-VGPR A/B frags), gfx90a-era builtin carried on gfx950.
// Device-compile guard: host pass lacks amdgcn MFMA builtins (R10 lesson).
__device__ __forceinline__ f32x4 mfma16(bf16x4 a, bf16x4 b, f32x4 c) {
#if defined(__HIP_DEVICE_COMPILE__)
    return __builtin_amdgcn_mfma_f32_16x16x16bf16_1k(a, b, c, 0, 0, 0);
#else
    (void)a; (void)b;
    return c;
#endif
}

// Direct global->LDS 16B DMA (m97). LDS dst is wave-uniform base + lane*16.
__device__ __forceinline__ void gld_lds16(const unsigned short* g, unsigned short* l) {
#if __has_builtin(__builtin_amdgcn_global_load_lds)
    __builtin_amdgcn_global_load_lds(
        (const __attribute__((address_space(1))) unsigned int*)g,
        (__attribute__((address_space(3))) unsigned int*)l, 16, 0, 0);
#else
    *(bf16x8*)l = *(const bf16x8*)g;
#endif
}

// ---------------- merged prep: cvt(x) + transpose-cvt(Wqkv) + transpose-cvt(Wout) ----
__global__ void __launch_bounds__(256) k_prep(const float* __restrict__ x,
                                              unsigned short* __restrict__ xb,
                                              const float* __restrict__ wqkv,
                                              unsigned short* __restrict__ wqkvt,
                                              const float* __restrict__ wout,
                                              unsigned short* __restrict__ woutt) {
    int bid = blockIdx.x;
    int tid = threadIdx.x;
    if (bid < 4096) {
        int i = (bid * 256 + tid) * 4;
        float4 v = *(const float4*)(x + i);
        union { ushort4 v; unsigned short s[4]; } o;
        o.s[0] = f2bf(v.x); o.s[1] = f2bf(v.y); o.s[2] = f2bf(v.z); o.s[3] = f2bf(v.w);
        *(ushort4*)(xb + i) = o.v;
        return;
    }
    const float* W; unsigned short* Wt; int N, t;
    if (bid < 7168) { W = wqkv; Wt = wqkvt; N = 3 * DM; t = bid - 4096; }
    else            { W = wout; Wt = woutt; N = DM;     t = bid - 7168; }
    int ntx = N >> 5;
    int bx = t % ntx, by = t / ntx;
    int tx = tid & 31, ty = tid >> 5;  // 32x8
    __shared__ float tile[32][33];
    for (int r = 0; r < 4; ++r) {
        int k = by * 32 + ty + r * 8;
        int n = bx * 32 + tx;
        tile[ty + r * 8][tx] = W[(size_t)k * N + n];
    }
    __syncthreads();
    for (int r = 0; r < 4; ++r) {
        int n = bx * 32 + ty + r * 8;
        int k = by * 32 + tx;
        Wt[(size_t)n * DM + k] = f2bf(tile[tx][ty + r * 8]);
    }
}

// ---------------- bf16 MFMA GEMM, 128x128 tile, B^T input ----------------
// BK=32, DMA staging double-buffered (R12), XOR chunk swizzle (0 conflicts).
// MODE 1 epilogue fuses RoPE (pair lives in adjacent lanes -> __shfl_xor(v,1)
// + 2 FMAs on fp32 acc BEFORE the single bf16 round) + Q exp2-unit pre-scale.
#define BKK 32

template <int MODE>
__device__ __forceinline__ void gemm_core(const unsigned short* __restrict__ A,
                                          const unsigned short* __restrict__ Bt,
                                          int K, int N,
                                          float* __restrict__ C,
                                          unsigned short* __restrict__ qbuf,
                                          unsigned short* __restrict__ kbuf,
                                          unsigned short* __restrict__ vt,
                                          const float* __restrict__ cosb,
                                          const float* __restrict__ sinb) {
    __shared__ unsigned short As0[128 * BKK];
    __shared__ unsigned short As1[128 * BKK];
    __shared__ unsigned short Bs0[128 * BKK];
    __shared__ unsigned short Bs1[128 * BKK];
    int tid = threadIdx.x;
    int lane = tid & 63, wave = tid >> 6;
    int row0 = blockIdx.y * 128;
    int col0 = blockIdx.x * 128;
    int wm = (wave >> 1) * 64, wn = (wave & 1) * 64;
    int fr = lane & 15;
    int quad = lane >> 4;

    f32x4 zero4 = {0.f, 0.f, 0.f, 0.f};
    f32x4 acc[4][4];
    for (int i = 0; i < 4; ++i)
        for (int j = 0; j < 4; ++j) acc[i][j] = zero4;

    auto stage = [&](unsigned short* Ad, unsigned short* Bd, int k0) {
        for (int i = 0; i < 2; ++i) {
            int s2 = i * 256 + tid;
            int r = s2 >> 2, kc = s2 & 3;
            int kk = (kc ^ (r & 3)) * 8;
            gld_lds16(A + (size_t)(row0 + r) * K + k0 + kk, Ad + (i * 256 + wave * 64) * 8);
            gld_lds16(Bt + (size_t)(col0 + r) * K + k0 + kk, Bd + (i * 256 + wave * 64) * 8);
        }
    };
    auto compute = [&](const unsigned short* Al, const unsigned short* Bl) {
        bf16x8 af[4], bf[4];
        for (int i = 0; i < 4; ++i) {
            int rr = wm + i * 16 + fr;
            af[i] = *(const bf16x8*)&Al[rr * BKK + ((quad ^ (rr & 3)) * 8)];
        }
        for (int j = 0; j < 4; ++j) {
            int rr = wn + j * 16 + fr;
            bf[j] = *(const bf16x8*)&Bl[rr * BKK + ((quad ^ (rr & 3)) * 8)];
        }
        for (int i = 0; i < 4; ++i)
            for (int j = 0; j < 4; ++j)
                acc[i][j] = __builtin_amdgcn_mfma_f32_16x16x32_bf16(af[i], bf[j], acc[i][j], 0, 0, 0);
    };

    stage(As0, Bs0, 0);
    __syncthreads();  // tile 0 DMA drained
    for (int k0 = 0; k0 < K; k0 += 2 * BKK) {  // K multiple of 64
        if (k0 + BKK < K) stage(As1, Bs1, k0 + BKK);
        compute(As0, Bs0);
        __syncthreads();
        if (k0 + 2 * BKK < K) stage(As0, Bs0, k0 + 2 * BKK);
        compute(As1, Bs1);
        __syncthreads();
    }

    int rq = (lane >> 4) * 4;
    int cq = lane & 15;
    const float qsc = 0.125f * 1.44269504f;  // softmax scale * log2(e)
    for (int i = 0; i < 4; ++i)
        for (int j = 0; j < 4; ++j)
            for (int reg = 0; reg < 4; ++reg) {
                int row = row0 + wm + i * 16 + rq + reg;  // token index
                int col = col0 + wn + j * 16 + cq;        // output col
                float v = acc[i][j][reg];
                if (MODE == 0) {
                    C[(size_t)row * N + col] = v;
                } else {
                    float pv = __shfl_xor(v, 1);  // rope partner (col^1 = lane^1)
                    int which = col >> 10;
                    int hc = col & 1023;
                    int h = hc >> 6, d = hc & 63;
                    int b = row >> 11, s = row & (SEQ - 1);
                    int bh = b * NH + h;
                    float outv = v;
                    if (which < 2) {  // rope q and k on fp32 acc
                        float cc = cosb[s * 32 + (d >> 1)];
                        float ss = sinb[s * 32 + (d >> 1)];
                        if (col & 1) outv = pv * ss + v * cc;   // x1*sin + x2*cos
                        else         outv = v * cc - pv * ss;   // x1*cos - x2*sin
                        if (which == 0) outv *= qsc;
                    }
                    unsigned short bv = f2bf(outv);
                    if (which == 0)      qbuf[((size_t)bh * SEQ + s) * HD + d] = bv;
                    else if (which == 1) kbuf[((size_t)bh * SEQ + s) * HD + d] = bv;
                    else                 vt[((size_t)bh * HD + d) * SEQ + s] = bv;
                }
            }
}

__global__ void __launch_bounds__(256) k_gemm_qkv(const unsigned short* __restrict__ A,
                                                  const unsigned short* __restrict__ Bt,
                                                  unsigned short* __restrict__ qbuf,
                                                  unsigned short* __restrict__ kbuf,
                                                  unsigned short* __restrict__ vt,
                                                  const float* __restrict__ cosb,
                                                  const float* __restrict__ sinb) {
    gemm_core<1>(A, Bt, DM, 3 * DM, nullptr, qbuf, kbuf, vt, cosb, sinb);
}

__global__ void __launch_bounds__(256) k_gemm_out(const unsigned short* __restrict__ A,
                                                  const unsigned short* __restrict__ Bt,
                                                  float* __restrict__ C) {
    gemm_core<0>(A, Bt, DM, DM, C, nullptr, nullptr, nullptr, nullptr, nullptr);
}

// ---------------- Flash attention: S^T trick + DMA dbuf + swizzled LDS ----
// (R13 structure; this round: P pack via v_cvt_pk_bf16_f32 — the manual
// f2bf pack was ~1/4 of the 26% VALUBusy.)
__global__ void __launch_bounds__(256, 4) k_attn(const unsigned short* __restrict__ qbuf,
                                                 const unsigned short* __restrict__ kbuf,
                                                 const unsigned short* __restrict__ vt,
                                                 unsigned short* __restrict__ obuf) {
    __shared__ unsigned short Ks0[64 * 64];
    __shared__ unsigned short Ks1[64 * 64];
    __shared__ unsigned short Vs0[64 * 64];
    __shared__ unsigned short Vs1[64 * 64];

    int tid = threadIdx.x;
    int lane = tid & 63, wave = tid >> 6;
    int bh = blockIdx.y;
    int b = bh >> 4, h = bh & 15;
    int qt = (int)gridDim.x - 1 - (int)blockIdx.x;  // biggest-work blocks dispatch first
    int qb = qt * 64;
    int fr = lane & 15, quad = lane >> 4;
    int Qmin = qb + wave * 16;

    const unsigned short* Qb = qbuf + (size_t)bh * SEQ * HD;
    const unsigned short* Kb = kbuf + (size_t)bh * SEQ * HD;
    const unsigned short* Vb = vt + (size_t)bh * HD * SEQ;

    // Q B-frags (n=query=fr, k-chunk=quad) — roped & pre-scaled in qkv epilogue.
    int qrow = Qmin + fr;
    bf16x8 qf0 = *(const bf16x8*)(Qb + (size_t)qrow * HD + quad * 8);
    bf16x8 qf1 = *(const bf16x8*)(Qb + (size_t)qrow * HD + 32 + quad * 8);

    f32x4 zero4 = {0.f, 0.f, 0.f, 0.f};
    f32x4 o[4];
    for (int j = 0; j < 4; ++j) o[j] = zero4;
    float l = 0.f;  // partial softmax denom for query fr (this lane's 16 keys/tile)

    // DMA staging with XOR granule swizzle at the source address.
    auto stage = [&](int kb, unsigned short* Kd, unsigned short* Vd) {
        for (int a = 0; a < 2; ++a) {
            int idx = a * 256 + tid;
            int r = idx >> 3;
            int lg = (idx & 7) ^ (r & 7);
            gld_lds16(Kb + (size_t)(kb + r) * HD + lg * 8, Kd + (a * 256 + wave * 64) * 8);
            gld_lds16(Vb + (size_t)r * SEQ + kb + lg * 8, Vd + (a * 256 + wave * 64) * 8);
        }
    };

    auto compute = [&](int kt, const unsigned short* Kd, const unsigned short* Vd) {
        int kb = kt * 64;
        int sw = fr & 7;
        // ---- S^T = K·Q^T: A=K frag (m=key), B=Q frag (n=query) ----
        f32x4 sg[4];
        for (int g = 0; g < 4; ++g) {
            int r = g * 16 + fr;
            bf16x8 ka = *(const bf16x8*)&Kd[r * 64 + ((quad ^ sw) * 8)];
            bf16x8 kc = *(const bf16x8*)&Kd[r * 64 + (((quad + 4) ^ sw) * 8)];
            f32x4 z = zero4;
            z = __builtin_amdgcn_mfma_f32_16x16x32_bf16(ka, qf0, z, 0, 0, 0);
            z = __builtin_amdgcn_mfma_f32_16x16x32_bf16(kc, qf1, z, 0, 0, 0);
            sg[g] = z;
        }
        // ---- causal mask: only each wave's diagonal tile ----
        if (kt == qt) {
            int q = Qmin + fr;
            for (int g = 0; g < 4; ++g)
                for (int reg = 0; reg < 4; ++reg)
                    if (kb + g * 16 + quad * 4 + reg > q) sg[g][reg] = -1e30f;
        }
        // ---- p = exp2(s); HW-packed to bf16 A-frags; l partial ----
        bf16x4 pf[4];
        for (int g = 0; g < 4; ++g) {
            float p0 = fexp2(sg[g][0]);
            float p1 = fexp2(sg[g][1]);
            float p2 = fexp2(sg[g][2]);
            float p3 = fexp2(sg[g][3]);
            l += (p0 + p1) + (p2 + p3);
            union { bf16x4 v; unsigned u[2]; } pc;
            pc.u[0] = pkbf16(p0, p1);
            pc.u[1] = pkbf16(p2, p3);
            pf[g] = pc.v;
        }
        // ---- PV in registers: V frag at logical shorts g*16+quad*4 of row d ----
        for (int g = 0; g < 4; ++g)
            for (int db = 0; db < 4; ++db) {
                int d = db * 16 + fr;
                int pg = ((2 * g + (quad >> 1)) ^ sw) * 8 + (quad & 1) * 4;
                bf16x4 vf = *(const bf16x4*)&Vd[d * 64 + pg];
                o[db] = mfma16(pf[g], vf, o[db]);
            }
    };

    stage(0, Ks0, Vs0);
    __syncthreads();  // tile 0 DMA drained
    for (int kt = 0; kt <= qt; kt += 2) {
        if (kt + 1 <= qt) stage((kt + 1) * 64, Ks1, Vs1);
        compute(kt, Ks0, Vs0);
        __syncthreads();  // Ks0/Vs0 readers done; Ks1/Vs1 DMA drained
        if (kt + 1 <= qt) {
            if (kt + 2 <= qt) stage((kt + 2) * 64, Ks0, Vs0);
            compute(kt + 1, Ks1, Vs1);
            __syncthreads();
        }
    }

    // ---- finish l: butterfly across quads; redistribute per o-row layout ----
    l += __shfl_xor(l, 16);
    l += __shfl_xor(l, 32);
    float linv[4];
    for (int reg = 0; reg < 4; ++reg)
        linv[reg] = frcp(__shfl(l, quad * 4 + reg));

    for (int db = 0; db < 4; ++db)
        for (int reg = 0; reg < 4; ++reg) {
            int s = Qmin + quad * 4 + reg;
            int d = db * 16 + fr;
            obuf[((size_t)(b * SEQ + s)) * DM + h * HD + d] = f2bf(o[db][reg] * linv[reg]);
        }
}

extern "C" void kernel_launch(void* const* d_in, const int* in_sizes, int n_in,
                              void* d_out, int out_size, void* d_ws, size_t ws_size,
                              hipStream_t stream) {
    const float* x    = (const float*)d_in[0];
    const float* rc   = (const float*)d_in[1];
    const float* rs   = (const float*)d_in[2];
    const float* wqkv = (const float*)d_in[3];
    const float* wout = (const float*)d_in[4];
    float* out = (float*)d_out;

    char* ws = (char*)d_ws;
    size_t off = 0;
    auto alloc = [&](size_t bytes) {
        char* p = ws + off;
        off += (bytes + 255) & ~(size_t)255;
        return p;
    };
    unsigned short* xb    = (unsigned short*)alloc((size_t)TOK * DM * 2);
    unsigned short* wqkvt = (unsigned short*)alloc((size_t)3 * DM * DM * 2);
    unsigned short* woutt = (unsigned short*)alloc((size_t)DM * DM * 2);
    unsigned short* qbuf  = (unsigned short*)alloc((size_t)BATCH * NH * SEQ * HD * 2);
    unsigned short* kbuf  = (unsigned short*)alloc((size_t)BATCH * NH * SEQ * HD * 2);
    unsigned short* vtb   = (unsigned short*)alloc((size_t)BATCH * NH * SEQ * HD * 2);
    unsigned short* obuf  = (unsigned short*)alloc((size_t)TOK * DM * 2);

    k_prep<<<8192, 256, 0, stream>>>(x, xb, wqkv, wqkvt, wout, woutt);
    k_gemm_qkv<<<dim3(3 * DM / 128, TOK / 128), 256, 0, stream>>>(xb, wqkvt, qbuf, kbuf, vtb, rc, rs);
    k_attn<<<dim3(SEQ / 64, BATCH * NH), 256, 0, stream>>>(qbuf, kbuf, vtb, obuf);
    k_gemm_out<<<dim3(DM / 128, TOK / 128), 256, 0, stream>>>(obuf, woutt, out);
}

// Round 15
// 197.140 us; speedup vs baseline: 1.1305x; 1.1305x over previous
//
#include <hip/hip_runtime.h>
#include <hip/hip_bf16.h>
#include <stdint.h>

typedef short bf16x8 __attribute__((ext_vector_type(8)));
typedef short bf16x4 __attribute__((ext_vector_type(4)));
typedef float f32x4 __attribute__((ext_vector_type(4)));

#define HD 64
#define NH 16
#define SEQ 2048
#define BATCH 2
#define DM 1024
#define TOK (BATCH * SEQ)

__device__ __forceinline__ unsigned short f2bf(float f) {
    union { float f; unsigned u; } a; a.f = f;
    unsigned r = a.u + 0x7fffu + ((a.u >> 16) & 1u);
    return (unsigned short)(r >> 16);
}
__device__ __forceinline__ float bf2f(unsigned short u) {
    union { unsigned u; float f; } a; a.u = ((unsigned)u) << 16;
    return a.f;
}

// HW-packed 2xf32 -> 2xbf16 (v_cvt_pk_bf16_f32 on gfx950; one VALU op).
__device__ __forceinline__ unsigned pkbf16(float a, float b) {
    union { __hip_bfloat162 h; unsigned u; } cv;
    cv.h = __float22bfloat162_rn(make_float2(a, b));
    return cv.u;
}

__device__ __forceinline__ float fexp2(float x) {
#if __has_builtin(__builtin_amdgcn_exp2f)
    return __builtin_amdgcn_exp2f(x);
#else
    return exp2f(x);
#endif
}
__device__ __forceinline__ float frcp(float x) {
#if __has_builtin(__builtin_amdgcn_rcpf)
    return __builtin_amdgcn_rcpf(x);
#else
    return 1.0f / x;
#endif
}

// 16x16x16 bf16 MFMA (2-VGPR A/B frags), gfx90a-era builtin carried on gfx950.
// Device-compile guard: host pass lacks amdgcn MFMA builtins (R10 lesson).
__device__ __forceinline__ f32x4 mfma16(bf16x4 a, bf16x4 b, f32x4 c) {
#if defined(__HIP_DEVICE_COMPILE__)
    return __builtin_amdgcn_mfma_f32_16x16x16bf16_1k(a, b, c, 0, 0, 0);
#else
    (void)a; (void)b;
    return c;
#endif
}

// Direct global->LDS 16B DMA (m97). LDS dst is wave-uniform base + lane*16.
__device__ __forceinline__ void gld_lds16(const unsigned short* g, unsigned short* l) {
#if __has_builtin(__builtin_amdgcn_global_load_lds)
    __builtin_amdgcn_global_load_lds(
        (const __attribute__((address_space(1))) unsigned int*)g,
        (__attribute__((address_space(3))) unsigned int*)l, 16, 0, 0);
#else
    *(bf16x8*)l = *(const bf16x8*)g;
#endif
}

// ---------------- merged prep: cvt(x) + transpose-cvt(Wqkv) + transpose-cvt(Wout) ----
__global__ void __launch_bounds__(256) k_prep(const float* __restrict__ x,
                                              unsigned short* __restrict__ xb,
                                              const float* __restrict__ wqkv,
                                              unsigned short* __restrict__ wqkvt,
                                              const float* __restrict__ wout,
                                              unsigned short* __restrict__ woutt) {
    int bid = blockIdx.x;
    int tid = threadIdx.x;
    if (bid < 4096) {
        int i = (bid * 256 + tid) * 4;
        float4 v = *(const float4*)(x + i);
        union { ushort4 v; unsigned short s[4]; } o;
        o.s[0] = f2bf(v.x); o.s[1] = f2bf(v.y); o.s[2] = f2bf(v.z); o.s[3] = f2bf(v.w);
        *(ushort4*)(xb + i) = o.v;
        return;
    }
    const float* W; unsigned short* Wt; int N, t;
    if (bid < 7168) { W = wqkv; Wt = wqkvt; N = 3 * DM; t = bid - 4096; }
    else            { W = wout; Wt = woutt; N = DM;     t = bid - 7168; }
    int ntx = N >> 5;
    int bx = t % ntx, by = t / ntx;
    int tx = tid & 31, ty = tid >> 5;  // 32x8
    __shared__ float tile[32][33];
    for (int r = 0; r < 4; ++r) {
        int k = by * 32 + ty + r * 8;
        int n = bx * 32 + tx;
        tile[ty + r * 8][tx] = W[(size_t)k * N + n];
    }
    __syncthreads();
    for (int r = 0; r < 4; ++r) {
        int n = bx * 32 + ty + r * 8;
        int k = by * 32 + tx;
        Wt[(size_t)n * DM + k] = f2bf(tile[tx][ty + r * 8]);
    }
}

// ---------------- bf16 MFMA GEMM, 128x128 tile, B^T input ----------------
// BK=32, DMA staging double-buffered (R12: 83->~55us), XOR chunk swizzle.
// Plain epilogue — R14's RoPE-fused epilogue REGRESSED (+24us): 128 scattered
// 4B cos/sin loads/thread at 14% occupancy; the standalone k_rope's coalesced
// bf16x8 traffic costs only ~6us. Fusion must ride existing traffic, not
// create scattered traffic.
#define BKK 32

template <int MODE>
__device__ __forceinline__ void gemm_core(const unsigned short* __restrict__ A,
                                          const unsigned short* __restrict__ Bt,
                                          int K, int N,
                                          float* __restrict__ C,
                                          unsigned short* __restrict__ qbuf,
                                          unsigned short* __restrict__ kbuf,
                                          unsigned short* __restrict__ vt) {
    __shared__ unsigned short As0[128 * BKK];
    __shared__ unsigned short As1[128 * BKK];
    __shared__ unsigned short Bs0[128 * BKK];
    __shared__ unsigned short Bs1[128 * BKK];
    int tid = threadIdx.x;
    int lane = tid & 63, wave = tid >> 6;
    int row0 = blockIdx.y * 128;
    int col0 = blockIdx.x * 128;
    int wm = (wave >> 1) * 64, wn = (wave & 1) * 64;
    int fr = lane & 15;
    int quad = lane >> 4;

    f32x4 zero4 = {0.f, 0.f, 0.f, 0.f};
    f32x4 acc[4][4];
    for (int i = 0; i < 4; ++i)
        for (int j = 0; j < 4; ++j) acc[i][j] = zero4;

    auto stage = [&](unsigned short* Ad, unsigned short* Bd, int k0) {
        for (int i = 0; i < 2; ++i) {
            int s2 = i * 256 + tid;
            int r = s2 >> 2, kc = s2 & 3;
            int kk = (kc ^ (r & 3)) * 8;
            gld_lds16(A + (size_t)(row0 + r) * K + k0 + kk, Ad + (i * 256 + wave * 64) * 8);
            gld_lds16(Bt + (size_t)(col0 + r) * K + k0 + kk, Bd + (i * 256 + wave * 64) * 8);
        }
    };
    auto compute = [&](const unsigned short* Al, const unsigned short* Bl) {
        bf16x8 af[4], bf[4];
        for (int i = 0; i < 4; ++i) {
            int rr = wm + i * 16 + fr;
            af[i] = *(const bf16x8*)&Al[rr * BKK + ((quad ^ (rr & 3)) * 8)];
        }
        for (int j = 0; j < 4; ++j) {
            int rr = wn + j * 16 + fr;
            bf[j] = *(const bf16x8*)&Bl[rr * BKK + ((quad ^ (rr & 3)) * 8)];
        }
        for (int i = 0; i < 4; ++i)
            for (int j = 0; j < 4; ++j)
                acc[i][j] = __builtin_amdgcn_mfma_f32_16x16x32_bf16(af[i], bf[j], acc[i][j], 0, 0, 0);
    };

    stage(As0, Bs0, 0);
    __syncthreads();  // tile 0 DMA drained
    for (int k0 = 0; k0 < K; k0 += 2 * BKK) {  // K multiple of 64
        if (k0 + BKK < K) stage(As1, Bs1, k0 + BKK);
        compute(As0, Bs0);
        __syncthreads();
        if (k0 + 2 * BKK < K) stage(As0, Bs0, k0 + 2 * BKK);
        compute(As1, Bs1);
        __syncthreads();
    }

    int rq = (lane >> 4) * 4;
    int cq = lane & 15;
    for (int i = 0; i < 4; ++i)
        for (int j = 0; j < 4; ++j)
            for (int reg = 0; reg < 4; ++reg) {
                int row = row0 + wm + i * 16 + rq + reg;  // token index
                int col = col0 + wn + j * 16 + cq;        // output col
                float v = acc[i][j][reg];
                if (MODE == 0) {
                    C[(size_t)row * N + col] = v;
                } else {
                    int which = col >> 10;
                    int hc = col & 1023;
                    int h = hc >> 6, d = hc & 63;
                    int b = row >> 11, s = row & (SEQ - 1);
                    int bh = b * NH + h;
                    unsigned short bv = f2bf(v);
                    if (which == 0)      qbuf[((size_t)bh * SEQ + s) * HD + d] = bv;
                    else if (which == 1) kbuf[((size_t)bh * SEQ + s) * HD + d] = bv;
                    else                 vt[((size_t)bh * HD + d) * SEQ + s] = bv;
                }
            }
}

__global__ void __launch_bounds__(256) k_gemm_qkv(const unsigned short* __restrict__ A,
                                                  const unsigned short* __restrict__ Bt,
                                                  unsigned short* __restrict__ qbuf,
                                                  unsigned short* __restrict__ kbuf,
                                                  unsigned short* __restrict__ vt) {
    gemm_core<1>(A, Bt, DM, 3 * DM, nullptr, qbuf, kbuf, vt);
}

__global__ void __launch_bounds__(256) k_gemm_out(const unsigned short* __restrict__ A,
                                                  const unsigned short* __restrict__ Bt,
                                                  float* __restrict__ C) {
    gemm_core<0>(A, Bt, DM, DM, C, nullptr, nullptr, nullptr);
}

// ---------------- RoPE in place on Q and K ----------------
// Q additionally pre-scaled by softmax_scale * log2(e) so attention scores
// come out of QK^T already in exp2 units.
__global__ void k_rope(unsigned short* __restrict__ qbuf, unsigned short* __restrict__ kbuf,
                       const float* __restrict__ cosb, const float* __restrict__ sinb) {
    int t = blockIdx.x * 256 + threadIdx.x;
    int c = t & 7;
    int row = (t >> 3) & 65535;
    int which = t >> 19;
    unsigned short* p = (which ? kbuf : qbuf) + (size_t)row * HD + c * 8;
    float sc = which ? 1.0f : (0.125f * 1.44269504f);  // 1/sqrt(64) * log2(e)
    int s = row & (SEQ - 1);
    const float* cs = cosb + s * 32 + c * 4;
    const float* sn = sinb + s * 32 + c * 4;
    bf16x8 v = *(const bf16x8*)p;
    bf16x8 o;
    for (int i = 0; i < 4; ++i) {
        float x1 = bf2f((unsigned short)v[2 * i]);
        float x2 = bf2f((unsigned short)v[2 * i + 1]);
        float cc = cs[i], ss = sn[i];
        o[2 * i]     = (short)f2bf((x1 * cc - x2 * ss) * sc);
        o[2 * i + 1] = (short)f2bf((x1 * ss + x2 * cc) * sc);
    }
    *(bf16x8*)p = o;
}

// ---------------- Flash attention: S^T trick + DMA dbuf + swizzled LDS ----
// (R13 structure + R14's pkbf16 P-pack, which is kept: one v_cvt_pk_bf16_f32
// replaces ~10 manual pack ops — the manual pack was ~1/4 of 26% VALUBusy.)
__global__ void __launch_bounds__(256, 4) k_attn(const unsigned short* __restrict__ qbuf,
                                                 const unsigned short* __restrict__ kbuf,
                                                 const unsigned short* __restrict__ vt,
                                                 unsigned short* __restrict__ obuf) {
    __shared__ unsigned short Ks0[64 * 64];
    __shared__ unsigned short Ks1[64 * 64];
    __shared__ unsigned short Vs0[64 * 64];
    __shared__ unsigned short Vs1[64 * 64];

    int tid = threadIdx.x;
    int lane = tid & 63, wave = tid >> 6;
    int bh = blockIdx.y;
    int b = bh >> 4, h = bh & 15;
    int qt = (int)gridDim.x - 1 - (int)blockIdx.x;  // biggest-work blocks dispatch first
    int qb = qt * 64;
    int fr = lane & 15, quad = lane >> 4;
    int Qmin = qb + wave * 16;

    const unsigned short* Qb = qbuf + (size_t)bh * SEQ * HD;
    const unsigned short* Kb = kbuf + (size_t)bh * SEQ * HD;
    const unsigned short* Vb = vt + (size_t)bh * HD * SEQ;

    // Q B-frags (n=query=fr, k-chunk=quad) — roped & pre-scaled by k_rope.
    int qrow = Qmin + fr;
    bf16x8 qf0 = *(const bf16x8*)(Qb + (size_t)qrow * HD + quad * 8);
    bf16x8 qf1 = *(const bf16x8*)(Qb + (size_t)qrow * HD + 32 + quad * 8);

    f32x4 zero4 = {0.f, 0.f, 0.f, 0.f};
    f32x4 o[4];
    for (int j = 0; j < 4; ++j) o[j] = zero4;
    float l = 0.f;  // partial softmax denom for query fr (this lane's 16 keys/tile)

    // DMA staging with XOR granule swizzle at the source address.
    auto stage = [&](int kb, unsigned short* Kd, unsigned short* Vd) {
        for (int a = 0; a < 2; ++a) {
            int idx = a * 256 + tid;
            int r = idx >> 3;
            int lg = (idx & 7) ^ (r & 7);
            gld_lds16(Kb + (size_t)(kb + r) * HD + lg * 8, Kd + (a * 256 + wave * 64) * 8);
            gld_lds16(Vb + (size_t)r * SEQ + kb + lg * 8, Vd + (a * 256 + wave * 64) * 8);
        }
    };

    auto compute = [&](int kt, const unsigned short* Kd, const unsigned short* Vd) {
        int kb = kt * 64;
        int sw = fr & 7;
        // ---- S^T = K·Q^T: A=K frag (m=key), B=Q frag (n=query) ----
        f32x4 sg[4];
        for (int g = 0; g < 4; ++g) {
            int r = g * 16 + fr;
            bf16x8 ka = *(const bf16x8*)&Kd[r * 64 + ((quad ^ sw) * 8)];
            bf16x8 kc = *(const bf16x8*)&Kd[r * 64 + (((quad + 4) ^ sw) * 8)];
            f32x4 z = zero4;
            z = __builtin_amdgcn_mfma_f32_16x16x32_bf16(ka, qf0, z, 0, 0, 0);
            z = __builtin_amdgcn_mfma_f32_16x16x32_bf16(kc, qf1, z, 0, 0, 0);
            sg[g] = z;
        }
        // ---- causal mask: only each wave's diagonal tile ----
        if (kt == qt) {
            int q = Qmin + fr;
            for (int g = 0; g < 4; ++g)
                for (int reg = 0; reg < 4; ++reg)
                    if (kb + g * 16 + quad * 4 + reg > q) sg[g][reg] = -1e30f;
        }
        // ---- p = exp2(s); HW-packed to bf16 A-frags; l partial ----
        bf16x4 pf[4];
        for (int g = 0; g < 4; ++g) {
            float p0 = fexp2(sg[g][0]);
            float p1 = fexp2(sg[g][1]);
            float p2 = fexp2(sg[g][2]);
            float p3 = fexp2(sg[g][3]);
            l += (p0 + p1) + (p2 + p3);
            union { bf16x4 v; unsigned u[2]; } pc;
            pc.u[0] = pkbf16(p0, p1);
            pc.u[1] = pkbf16(p2, p3);
            pf[g] = pc.v;
        }
        // ---- PV in registers: V frag at logical shorts g*16+quad*4 of row d ----
        for (int g = 0; g < 4; ++g)
            for (int db = 0; db < 4; ++db) {
                int d = db * 16 + fr;
                int pg = ((2 * g + (quad >> 1)) ^ sw) * 8 + (quad & 1) * 4;
                bf16x4 vf = *(const bf16x4*)&Vd[d * 64 + pg];
                o[db] = mfma16(pf[g], vf, o[db]);
            }
    };

    stage(0, Ks0, Vs0);
    __syncthreads();  // tile 0 DMA drained
    for (int kt = 0; kt <= qt; kt += 2) {
        if (kt + 1 <= qt) stage((kt + 1) * 64, Ks1, Vs1);
        compute(kt, Ks0, Vs0);
        __syncthreads();  // Ks0/Vs0 readers done; Ks1/Vs1 DMA drained
        if (kt + 1 <= qt) {
            if (kt + 2 <= qt) stage((kt + 2) * 64, Ks0, Vs0);
            compute(kt + 1, Ks1, Vs1);
            __syncthreads();
        }
    }

    // ---- finish l: butterfly across quads; redistribute per o-row layout ----
    l += __shfl_xor(l, 16);
    l += __shfl_xor(l, 32);
    float linv[4];
    for (int reg = 0; reg < 4; ++reg)
        linv[reg] = frcp(__shfl(l, quad * 4 + reg));

    for (int db = 0; db < 4; ++db)
        for (int reg = 0; reg < 4; ++reg) {
            int s = Qmin + quad * 4 + reg;
            int d = db * 16 + fr;
            obuf[((size_t)(b * SEQ + s)) * DM + h * HD + d] = f2bf(o[db][reg] * linv[reg]);
        }
}

extern "C" void kernel_launch(void* const* d_in, const int* in_sizes, int n_in,
                              void* d_out, int out_size, void* d_ws, size_t ws_size,
                              hipStream_t stream) {
    const float* x    = (const float*)d_in[0];
    const float* rc   = (const float*)d_in[1];
    const float* rs   = (const float*)d_in[2];
    const float* wqkv = (const float*)d_in[3];
    const float* wout = (const float*)d_in[4];
    float* out = (float*)d_out;

    char* ws = (char*)d_ws;
    size_t off = 0;
    auto alloc = [&](size_t bytes) {
        char* p = ws + off;
        off += (bytes + 255) & ~(size_t)255;
        return p;
    };
    unsigned short* xb    = (unsigned short*)alloc((size_t)TOK * DM * 2);
    unsigned short* wqkvt = (unsigned short*)alloc((size_t)3 * DM * DM * 2);
    unsigned short* woutt = (unsigned short*)alloc((size_t)DM * DM * 2);
    unsigned short* qbuf  = (unsigned short*)alloc((size_t)BATCH * NH * SEQ * HD * 2);
    unsigned short* kbuf  = (unsigned short*)alloc((size_t)BATCH * NH * SEQ * HD * 2);
    unsigned short* vtb   = (unsigned short*)alloc((size_t)BATCH * NH * SEQ * HD * 2);
    unsigned short* obuf  = (unsigned short*)alloc((size_t)TOK * DM * 2);

    k_prep<<<8192, 256, 0, stream>>>(x, xb, wqkv, wqkvt, wout, woutt);
    k_gemm_qkv<<<dim3(3 * DM / 128, TOK / 128), 256, 0, stream>>>(xb, wqkvt, qbuf, kbuf, vtb);
    k_rope<<<4096, 256, 0, stream>>>(qbuf, kbuf, rc, rs);
    k_attn<<<dim3(SEQ / 64, BATCH * NH), 256, 0, stream>>>(qbuf, kbuf, vtb, obuf);
    k_gemm_out<<<dim3(DM / 128, TOK / 128), 256, 0, stream>>>(obuf, woutt, out);
}

// Round 16
// 196.523 us; speedup vs baseline: 1.1340x; 1.0031x over previous
//
#include <hip/hip_runtime.h>
#include <hip/hip_bf16.h>
#include <stdint.h>

typedef short bf16x8 __attribute__((ext_vector_type(8)));
typedef short bf16x4 __attribute__((ext_vector_type(4)));
typedef float f32x4 __attribute__((ext_vector_type(4)));

#define HD 64
#define NH 16
#define SEQ 2048
#define BATCH 2
#define DM 1024
#define TOK (BATCH * SEQ)

__device__ __forceinline__ unsigned short f2bf(float f) {
    union { float f; unsigned u; } a; a.f = f;
    unsigned r = a.u + 0x7fffu + ((a.u >> 16) & 1u);
    return (unsigned short)(r >> 16);
}
__device__ __forceinline__ float bf2f(unsigned short u) {
    union { unsigned u; float f; } a; a.u = ((unsigned)u) << 16;
    return a.f;
}

// HW-packed 2xf32 -> 2xbf16 (v_cvt_pk_bf16_f32 on gfx950; one VALU op).
__device__ __forceinline__ unsigned pkbf16(float a, float b) {
    union { __hip_bfloat162 h; unsigned u; } cv;
    cv.h = __float22bfloat162_rn(make_float2(a, b));
    return cv.u;
}

__device__ __forceinline__ float fexp2(float x) {
#if __has_builtin(__builtin_amdgcn_exp2f)
    return __builtin_amdgcn_exp2f(x);
#else
    return exp2f(x);
#endif
}
__device__ __forceinline__ float frcp(float x) {
#if __has_builtin(__builtin_amdgcn_rcpf)
    return __builtin_amdgcn_rcpf(x);
#else
    return 1.0f / x;
#endif
}

// 16x16x16 bf16 MFMA (2-VGPR A/B frags), gfx90a-era builtin carried on gfx950.
// Device-compile guard: host pass lacks amdgcn MFMA builtins (R10 lesson).
__device__ __forceinline__ f32x4 mfma16(bf16x4 a, bf16x4 b, f32x4 c) {
#if defined(__HIP_DEVICE_COMPILE__)
    return __builtin_amdgcn_mfma_f32_16x16x16bf16_1k(a, b, c, 0, 0, 0);
#else
    (void)a; (void)b;
    return c;
#endif
}

// Direct global->LDS 16B DMA (m97). LDS dst is wave-uniform base + lane*16.
__device__ __forceinline__ void gld_lds16(const unsigned short* g, unsigned short* l) {
#if __has_builtin(__builtin_amdgcn_global_load_lds)
    __builtin_amdgcn_global_load_lds(
        (const __attribute__((address_space(1))) unsigned int*)g,
        (__attribute__((address_space(3))) unsigned int*)l, 16, 0, 0);
#else
    *(bf16x8*)l = *(const bf16x8*)g;
#endif
}

// ---------------- merged prep: cvt(x) + transpose-cvt(Wqkv) + transpose-cvt(Wout) ----
__global__ void __launch_bounds__(256) k_prep(const float* __restrict__ x,
                                              unsigned short* __restrict__ xb,
                                              const float* __restrict__ wqkv,
                                              unsigned short* __restrict__ wqkvt,
                                              const float* __restrict__ wout,
                                              unsigned short* __restrict__ woutt) {
    int bid = blockIdx.x;
    int tid = threadIdx.x;
    if (bid < 4096) {
        int i = (bid * 256 + tid) * 4;
        float4 v = *(const float4*)(x + i);
        union { ushort4 v; unsigned short s[4]; } o;
        o.s[0] = f2bf(v.x); o.s[1] = f2bf(v.y); o.s[2] = f2bf(v.z); o.s[3] = f2bf(v.w);
        *(ushort4*)(xb + i) = o.v;
        return;
    }
    const float* W; unsigned short* Wt; int N, t;
    if (bid < 7168) { W = wqkv; Wt = wqkvt; N = 3 * DM; t = bid - 4096; }
    else            { W = wout; Wt = woutt; N = DM;     t = bid - 7168; }
    int ntx = N >> 5;
    int bx = t % ntx, by = t / ntx;
    int tx = tid & 31, ty = tid >> 5;  // 32x8
    __shared__ float tile[32][33];
    for (int r = 0; r < 4; ++r) {
        int k = by * 32 + ty + r * 8;
        int n = bx * 32 + tx;
        tile[ty + r * 8][tx] = W[(size_t)k * N + n];
    }
    __syncthreads();
    for (int r = 0; r < 4; ++r) {
        int n = bx * 32 + ty + r * 8;
        int k = by * 32 + tx;
        Wt[(size_t)n * DM + k] = f2bf(tile[tx][ty + r * 8]);
    }
}

// ---------------- bf16 MFMA GEMM, 128x128 tile, B^T input ----------------
// BK=32, DMA staging double-buffered (R12), XOR chunk swizzle (0 conflicts).
// Plain epilogue (R14's rope-fused epilogue regressed: scattered 4B loads).
#define BKK 32

template <int MODE>
__device__ __forceinline__ void gemm_core(const unsigned short* __restrict__ A,
                                          const unsigned short* __restrict__ Bt,
                                          int K, int N,
                                          float* __restrict__ C,
                                          unsigned short* __restrict__ qbuf,
                                          unsigned short* __restrict__ kbuf,
                                          unsigned short* __restrict__ vt) {
    __shared__ unsigned short As0[128 * BKK];
    __shared__ unsigned short As1[128 * BKK];
    __shared__ unsigned short Bs0[128 * BKK];
    __shared__ unsigned short Bs1[128 * BKK];
    int tid = threadIdx.x;
    int lane = tid & 63, wave = tid >> 6;
    int row0 = blockIdx.y * 128;
    int col0 = blockIdx.x * 128;
    int wm = (wave >> 1) * 64, wn = (wave & 1) * 64;
    int fr = lane & 15;
    int quad = lane >> 4;

    f32x4 zero4 = {0.f, 0.f, 0.f, 0.f};
    f32x4 acc[4][4];
    for (int i = 0; i < 4; ++i)
        for (int j = 0; j < 4; ++j) acc[i][j] = zero4;

    auto stage = [&](unsigned short* Ad, unsigned short* Bd, int k0) {
        for (int i = 0; i < 2; ++i) {
            int s2 = i * 256 + tid;
            int r = s2 >> 2, kc = s2 & 3;
            int kk = (kc ^ (r & 3)) * 8;
            gld_lds16(A + (size_t)(row0 + r) * K + k0 + kk, Ad + (i * 256 + wave * 64) * 8);
            gld_lds16(Bt + (size_t)(col0 + r) * K + k0 + kk, Bd + (i * 256 + wave * 64) * 8);
        }
    };
    auto compute = [&](const unsigned short* Al, const unsigned short* Bl) {
        bf16x8 af[4], bf[4];
        for (int i = 0; i < 4; ++i) {
            int rr = wm + i * 16 + fr;
            af[i] = *(const bf16x8*)&Al[rr * BKK + ((quad ^ (rr & 3)) * 8)];
        }
        for (int j = 0; j < 4; ++j) {
            int rr = wn + j * 16 + fr;
            bf[j] = *(const bf16x8*)&Bl[rr * BKK + ((quad ^ (rr & 3)) * 8)];
        }
        for (int i = 0; i < 4; ++i)
            for (int j = 0; j < 4; ++j)
                acc[i][j] = __builtin_amdgcn_mfma_f32_16x16x32_bf16(af[i], bf[j], acc[i][j], 0, 0, 0);
    };

    stage(As0, Bs0, 0);
    __syncthreads();  // tile 0 DMA drained
    for (int k0 = 0; k0 < K; k0 += 2 * BKK) {  // K multiple of 64
        if (k0 + BKK < K) stage(As1, Bs1, k0 + BKK);
        compute(As0, Bs0);
        __syncthreads();
        if (k0 + 2 * BKK < K) stage(As0, Bs0, k0 + 2 * BKK);
        compute(As1, Bs1);
        __syncthreads();
    }

    int rq = (lane >> 4) * 4;
    int cq = lane & 15;
    for (int i = 0; i < 4; ++i)
        for (int j = 0; j < 4; ++j)
            for (int reg = 0; reg < 4; ++reg) {
                int row = row0 + wm + i * 16 + rq + reg;  // token index
                int col = col0 + wn + j * 16 + cq;        // output col
                float v = acc[i][j][reg];
                if (MODE == 0) {
                    C[(size_t)row * N + col] = v;
                } else {
                    int which = col >> 10;
                    int hc = col & 1023;
                    int h = hc >> 6, d = hc & 63;
                    int b = row >> 11, s = row & (SEQ - 1);
                    int bh = b * NH + h;
                    unsigned short bv = f2bf(v);
                    if (which == 0)      qbuf[((size_t)bh * SEQ + s) * HD + d] = bv;
                    else if (which == 1) kbuf[((size_t)bh * SEQ + s) * HD + d] = bv;
                    else                 vt[((size_t)bh * HD + d) * SEQ + s] = bv;
                }
            }
}

__global__ void __launch_bounds__(256) k_gemm_qkv(const unsigned short* __restrict__ A,
                                                  const unsigned short* __restrict__ Bt,
                                                  unsigned short* __restrict__ qbuf,
                                                  unsigned short* __restrict__ kbuf,
                                                  unsigned short* __restrict__ vt) {
    gemm_core<1>(A, Bt, DM, 3 * DM, nullptr, qbuf, kbuf, vt);
}

__global__ void __launch_bounds__(256) k_gemm_out(const unsigned short* __restrict__ A,
                                                  const unsigned short* __restrict__ Bt,
                                                  float* __restrict__ C) {
    gemm_core<0>(A, Bt, DM, DM, C, nullptr, nullptr, nullptr);
}

// ---------------- RoPE in place on Q and K ----------------
// Q additionally pre-scaled by softmax_scale * log2(e) so attention scores
// come out of QK^T already in exp2 units.
__global__ void k_rope(unsigned short* __restrict__ qbuf, unsigned short* __restrict__ kbuf,
                       const float* __restrict__ cosb, const float* __restrict__ sinb) {
    int t = blockIdx.x * 256 + threadIdx.x;
    int c = t & 7;
    int row = (t >> 3) & 65535;
    int which = t >> 19;
    unsigned short* p = (which ? kbuf : qbuf) + (size_t)row * HD + c * 8;
    float sc = which ? 1.0f : (0.125f * 1.44269504f);  // 1/sqrt(64) * log2(e)
    int s = row & (SEQ - 1);
    const float* cs = cosb + s * 32 + c * 4;
    const float* sn = sinb + s * 32 + c * 4;
    bf16x8 v = *(const bf16x8*)p;
    bf16x8 o;
    for (int i = 0; i < 4; ++i) {
        float x1 = bf2f((unsigned short)v[2 * i]);
        float x2 = bf2f((unsigned short)v[2 * i + 1]);
        float cc = cs[i], ss = sn[i];
        o[2 * i]     = (short)f2bf((x1 * cc - x2 * ss) * sc);
        o[2 * i + 1] = (short)f2bf((x1 * ss + x2 * cc) * sc);
    }
    *(bf16x8*)p = o;
}

// ---------------- Flash attention: 32 queries/wave, 2-wave blocks ----------
// grid (SEQ/64, B*NH) = 1024 blocks x 128 threads (2 waves). Wave owns 32
// queries as TWO 16-query B-frag sets; K frags (8 b128) and V frags (16 b64)
// are read from LDS ONCE per tile and reused for both sets (fragment reads
// are query-count invariant), halving the per-query LDS traffic and address
// VALU vs R15's 16 q/wave (which spent ~18us on 80KB/block-tile LDS).
// Block-tile LDS: 2 waves x 16KB read + 16KB staged = 48KB per 64 queries.
// Same S^T trick (P in registers), DMA dbuf, XOR granule swizzle, no-max
// softmax. Trip count block-uniform (all waves iterate kt=0..qt; early-wave
// extra tiles fully masked -> exp2(-1e30)=0). LDS 32KB -> 4 blocks/CU.
__global__ void __launch_bounds__(128, 2) k_attn(const unsigned short* __restrict__ qbuf,
                                                 const unsigned short* __restrict__ kbuf,
                                                 const unsigned short* __restrict__ vt,
                                                 unsigned short* __restrict__ obuf) {
    __shared__ unsigned short Ks0[64 * 64];
    __shared__ unsigned short Ks1[64 * 64];
    __shared__ unsigned short Vs0[64 * 64];
    __shared__ unsigned short Vs1[64 * 64];

    int tid = threadIdx.x;             // 0..127
    int lane = tid & 63, wave = tid >> 6;  // wave 0..1
    int bh = blockIdx.y;
    int b = bh >> 4, h = bh & 15;
    int qt = (int)gridDim.x - 1 - (int)blockIdx.x;  // biggest-work blocks dispatch first
    int qb = qt * 64;
    int fr = lane & 15, quad = lane >> 4, sw = fr & 7;
    int Qmin = qb + wave * 32;  // this wave's 32 queries

    const unsigned short* Qb = qbuf + (size_t)bh * SEQ * HD;
    const unsigned short* Kb = kbuf + (size_t)bh * SEQ * HD;
    const unsigned short* Vb = vt + (size_t)bh * HD * SEQ;

    // Q B-frags, 2 sets of 16 queries (roped & pre-scaled by k_rope).
    bf16x8 qf[2][2];
    for (int s = 0; s < 2; ++s) {
        int qrow = Qmin + s * 16 + fr;
        qf[s][0] = *(const bf16x8*)(Qb + (size_t)qrow * HD + quad * 8);
        qf[s][1] = *(const bf16x8*)(Qb + (size_t)qrow * HD + 32 + quad * 8);
    }

    f32x4 zero4 = {0.f, 0.f, 0.f, 0.f};
    f32x4 o[2][4];
    for (int s = 0; s < 2; ++s)
        for (int j = 0; j < 4; ++j) o[s][j] = zero4;
    float l[2] = {0.f, 0.f};

    // DMA staging (128 threads): 512 16B-slots per K tile -> 4 issues each.
    auto stage = [&](int kb, unsigned short* Kd, unsigned short* Vd) {
        for (int a = 0; a < 4; ++a) {
            int idx = a * 128 + tid;
            int r = idx >> 3;
            int lg = (idx & 7) ^ (r & 7);
            gld_lds16(Kb + (size_t)(kb + r) * HD + lg * 8, Kd + (a * 128 + wave * 64) * 8);
            gld_lds16(Vb + (size_t)r * SEQ + kb + lg * 8, Vd + (a * 128 + wave * 64) * 8);
        }
    };

    auto compute = [&](int kt, const unsigned short* Kd, const unsigned short* Vd) {
        int kb = kt * 64;
        // ---- fragments once per tile, shared by both query sets ----
        bf16x8 ka[4], kc[4];
        for (int g = 0; g < 4; ++g) {
            int r = g * 16 + fr;
            ka[g] = *(const bf16x8*)&Kd[r * 64 + ((quad ^ sw) * 8)];
            kc[g] = *(const bf16x8*)&Kd[r * 64 + (((quad + 4) ^ sw) * 8)];
        }
        bf16x4 vf[4][4];
        for (int g = 0; g < 4; ++g)
            for (int db = 0; db < 4; ++db) {
                int d = db * 16 + fr;
                int pg = ((2 * g + (quad >> 1)) ^ sw) * 8 + (quad & 1) * 4;
                vf[g][db] = *(const bf16x4*)&Vd[d * 64 + pg];
            }
        // ---- two 16-query sets through QK -> softmax -> PV ----
        for (int s = 0; s < 2; ++s) {
            f32x4 sg[4];
            for (int g = 0; g < 4; ++g) {
                f32x4 z = zero4;
                z = __builtin_amdgcn_mfma_f32_16x16x32_bf16(ka[g], qf[s][0], z, 0, 0, 0);
                z = __builtin_amdgcn_mfma_f32_16x16x32_bf16(kc[g], qf[s][1], z, 0, 0, 0);
                sg[g] = z;
            }
            int Qs = Qmin + s * 16;
            if (kb + 63 > Qs) {  // any key could exceed the smallest query
                int q = Qs + fr;
                for (int g = 0; g < 4; ++g)
                    for (int reg = 0; reg < 4; ++reg)
                        if (kb + g * 16 + quad * 4 + reg > q) sg[g][reg] = -1e30f;
            }
            bf16x4 pf[4];
            for (int g = 0; g < 4; ++g) {
                float p0 = fexp2(sg[g][0]);
                float p1 = fexp2(sg[g][1]);
                float p2 = fexp2(sg[g][2]);
                float p3 = fexp2(sg[g][3]);
                l[s] += (p0 + p1) + (p2 + p3);
                union { bf16x4 v; unsigned u[2]; } pc;
                pc.u[0] = pkbf16(p0, p1);
                pc.u[1] = pkbf16(p2, p3);
                pf[g] = pc.v;
            }
            for (int g = 0; g < 4; ++g)
                for (int db = 0; db < 4; ++db)
                    o[s][db] = mfma16(pf[g], vf[g][db], o[s][db]);
        }
    };

    stage(0, Ks0, Vs0);
    __syncthreads();  // tile 0 DMA drained
    for (int kt = 0; kt <= qt; kt += 2) {
        if (kt + 1 <= qt) stage((kt + 1) * 64, Ks1, Vs1);
        compute(kt, Ks0, Vs0);
        __syncthreads();  // Ks0/Vs0 readers done; Ks1/Vs1 DMA drained
        if (kt + 1 <= qt) {
            if (kt + 2 <= qt) stage((kt + 2) * 64, Ks0, Vs0);
            compute(kt + 1, Ks1, Vs1);
            __syncthreads();
        }
    }

    // ---- per set: finish l across quads; store ----
    for (int s = 0; s < 2; ++s) {
        float ll = l[s];
        ll += __shfl_xor(ll, 16);
        ll += __shfl_xor(ll, 32);
        float linv[4];
        for (int reg = 0; reg < 4; ++reg)
            linv[reg] = frcp(__shfl(ll, quad * 4 + reg));
        int Qs = Qmin + s * 16;
        for (int db = 0; db < 4; ++db)
            for (int reg = 0; reg < 4; ++reg) {
                int row = Qs + quad * 4 + reg;
                int d = db * 16 + fr;
                obuf[((size_t)(b * SEQ + row)) * DM + h * HD + d] = f2bf(o[s][db][reg] * linv[reg]);
            }
    }
}

extern "C" void kernel_launch(void* const* d_in, const int* in_sizes, int n_in,
                              void* d_out, int out_size, void* d_ws, size_t ws_size,
                              hipStream_t stream) {
    const float* x    = (const float*)d_in[0];
    const float* rc   = (const float*)d_in[1];
    const float* rs   = (const float*)d_in[2];
    const float* wqkv = (const float*)d_in[3];
    const float* wout = (const float*)d_in[4];
    float* out = (float*)d_out;

    char* ws = (char*)d_ws;
    size_t off = 0;
    auto alloc = [&](size_t bytes) {
        char* p = ws + off;
        off += (bytes + 255) & ~(size_t)255;
        return p;
    };
    unsigned short* xb    = (unsigned short*)alloc((size_t)TOK * DM * 2);
    unsigned short* wqkvt = (unsigned short*)alloc((size_t)3 * DM * DM * 2);
    unsigned short* woutt = (unsigned short*)alloc((size_t)DM * DM * 2);
    unsigned short* qbuf  = (unsigned short*)alloc((size_t)BATCH * NH * SEQ * HD * 2);
    unsigned short* kbuf  = (unsigned short*)alloc((size_t)BATCH * NH * SEQ * HD * 2);
    unsigned short* vtb   = (unsigned short*)alloc((size_t)BATCH * NH * SEQ * HD * 2);
    unsigned short* obuf  = (unsigned short*)alloc((size_t)TOK * DM * 2);

    k_prep<<<8192, 256, 0, stream>>>(x, xb, wqkv, wqkvt, wout, woutt);
    k_gemm_qkv<<<dim3(3 * DM / 128, TOK / 128), 256, 0, stream>>>(xb, wqkvt, qbuf, kbuf, vtb);
    k_rope<<<4096, 256, 0, stream>>>(qbuf, kbuf, rc, rs);
    k_attn<<<dim3(SEQ / 64, BATCH * NH), 128, 0, stream>>>(qbuf, kbuf, vtb, obuf);
    k_gemm_out<<<dim3(DM / 128, TOK / 128), 256, 0, stream>>>(obuf, woutt, out);
}